// Round 8
// baseline (421.658 us; speedup 1.0000x reference)
//
#include <hip/hip_runtime.h>

#define DFEAT 128

typedef __attribute__((ext_vector_type(8))) short short8;
typedef __attribute__((ext_vector_type(4))) float float4v;

// ---------- bf16 helpers ----------
__device__ __forceinline__ float bf2f(unsigned int h) {
    union { unsigned int u; float f; } v; v.u = h << 16; return v.f;
}
__device__ __forceinline__ unsigned short f2bf(float f) {
    union { float f; unsigned int u; } v; v.f = f;
    unsigned int u = v.u;
    unsigned int lsb = (u >> 16) & 1u;
    u += 0x7fffu + lsb;               // RNE
    return (unsigned short)(u >> 16);
}

// ---------- fused: prep_w (blocks [0,128)) + packed-u64 histogram ----------
// dc[t] += (1<<48) | (u64)(w*2^40); atomic RETURN gives this edge's local position.
__global__ __launch_bounds__(256) void hist_kernel(
    const int* __restrict__ dstL, const float* __restrict__ wL,
    const int* __restrict__ dstG, const float* __restrict__ wG,
    const float* __restrict__ Wl, const float* __restrict__ Wg,
    unsigned short* __restrict__ WT,
    unsigned long long* __restrict__ dc,
    unsigned short* __restrict__ lp16, int El, int Eg, int n)
{
    if (blockIdx.x < 128) {
        int idx = blockIdx.x * 256 + threadIdx.x;     // 0 .. 32767
        int m = idx >> 14, rem = idx & 16383;
        int k = rem >> 7, c = rem & 127;
        const float* W = m ? Wg : Wl;
        WT[m * 16384 + c * 128 + k] = f2bf(W[k * 128 + c]);
        return;
    }
    int e = (blockIdx.x - 128) * 256 + threadIdx.x;
    if (e < El) {
        int t = dstL[e];
        unsigned long long add = (1ULL << 48) | (unsigned long long)(wL[e] * 0x1p40f);
        unsigned long long old = atomicAdd(&dc[t], add);
        lp16[e] = (unsigned short)(old >> 48);
    } else if (e < El + Eg) {
        int e2 = e - El;
        int t = dstG[e2];
        unsigned long long add = (1ULL << 48) | (unsigned long long)(wG[e2] * 0x1p40f);
        unsigned long long old = atomicAdd(&dc[n + t], add);
        lp16[e] = (unsigned short)(old >> 48);
    }
}

// ---------- scan stage 1: unpack dc -> (cnt scan into ptr, dinv) ----------
__global__ __launch_bounds__(256) void scan1_kernel(const unsigned long long* __restrict__ dc,
                                                    int* __restrict__ ptr,
                                                    int* __restrict__ bsum,
                                                    float* __restrict__ dinv, int n)
{
    __shared__ int tmp[256];
    int i = blockIdx.x * 256 + threadIdx.x;
    int v = 0;
    if (i < n) {
        unsigned long long d = dc[i];
        v = (int)(d >> 48);
        dinv[i] = rsqrtf((float)(d & ((1ULL << 48) - 1)) * 0x1p-40f + 1.0f);
    }
    tmp[threadIdx.x] = v;
    __syncthreads();
    for (int off = 1; off < 256; off <<= 1) {
        int t = (threadIdx.x >= off) ? tmp[threadIdx.x - off] : 0;
        __syncthreads();
        tmp[threadIdx.x] += t;
        __syncthreads();
    }
    if (i < n) ptr[i] = tmp[threadIdx.x] - v;       // exclusive within block
    if (threadIdx.x == 255) bsum[blockIdx.x] = tmp[255];
}

// ---------- scan stage 2: single block (nb <= 512) ----------
__global__ __launch_bounds__(512) void scan2_kernel(int* __restrict__ bsum, int nb)
{
    __shared__ int tmp[512];
    int i = threadIdx.x;
    int v = (i < nb) ? bsum[i] : 0;
    tmp[i] = v;
    __syncthreads();
    for (int off = 1; off < 512; off <<= 1) {
        int t = (i >= off) ? tmp[i - off] : 0;
        __syncthreads();
        tmp[i] += t;
        __syncthreads();
    }
    if (i < nb) bsum[i] = tmp[i] - v;
}

// ---------- scan stage 3 ----------
__global__ __launch_bounds__(256) void scan3_kernel(int* __restrict__ ptr,
                                                    const int* __restrict__ bsum, int n)
{
    int i = blockIdx.x * 256 + threadIdx.x;
    if (i < n) ptr[i] += bsum[blockIdx.x];
}

// ---------- edata placement: NO atomics (pos = ptr[t] + lp16[e]); ptr preserved ----------
__global__ __launch_bounds__(256) void edata_write_kernel(
    const int* __restrict__ srcL, const int* __restrict__ dstL, const float* __restrict__ wL,
    const int* __restrict__ srcG, const int* __restrict__ dstG, const float* __restrict__ wG,
    const float* __restrict__ dinv, const int* __restrict__ ptr,
    const unsigned short* __restrict__ lp16, int2* __restrict__ edata,
    int El, int Eg, int n)
{
    int e = blockIdx.x * 256 + threadIdx.x;
    if (e < El) {
        int s = srcL[e], t = dstL[e];
        float norm = dinv[s] * wL[e] * dinv[t];
        int pos = ptr[t] + lp16[e];
        edata[pos] = make_int2(__float_as_int(norm), s);
    } else if (e < El + Eg) {
        int e2 = e - El;
        int s = srcG[e2], t = dstG[e2];
        float norm = dinv[n + s] * wG[e2] * dinv[n + t];
        int pos = ptr[n + t] + lp16[e];
        edata[pos] = make_int2(__float_as_int(norm), s);
    }
}

// ---------- MFMA dual GEMM, no LDS; output in XCD-sliced layout [slice][node][16] ----------
__global__ __launch_bounds__(256) void gemm_kernel(
    const float* __restrict__ A, const float* __restrict__ L,
    const unsigned short* __restrict__ WT,   // [2][col 128][k 128] bf16
    unsigned short* __restrict__ xwl,
    unsigned short* __restrict__ xwg, int n)
{
    const int tid  = threadIdx.x;
    const int wid  = tid >> 6;
    const int lane = tid & 63;
    const int quad = lane >> 4;
    const int cl   = lane & 15;

    int rowa = blockIdx.x * 64 + wid * 16 + cl;
    if (rowa > n - 1) rowa = n - 1;               // clamp (dup compute, stores predicated)

    const float* Ar = A + (size_t)rowa * DFEAT;
    const float* Lr = L + (size_t)rowa * DFEAT;

    short8 a[4];
    #pragma unroll
    for (int kk = 0; kk < 4; ++kk) {
        const int kb = kk * 32 + quad * 8;
        float4 a0 = *(const float4*)&Ar[kb];
        float4 a1 = *(const float4*)&Ar[kb + 4];
        float4 l0 = *(const float4*)&Lr[kb];
        float4 l1 = *(const float4*)&Lr[kb + 4];
        union { short8 v; unsigned short u[8]; } s;
        s.u[0] = f2bf(a0.x + l0.x); s.u[1] = f2bf(a0.y + l0.y);
        s.u[2] = f2bf(a0.z + l0.z); s.u[3] = f2bf(a0.w + l0.w);
        s.u[4] = f2bf(a1.x + l1.x); s.u[5] = f2bf(a1.y + l1.y);
        s.u[6] = f2bf(a1.z + l1.z); s.u[7] = f2bf(a1.w + l1.w);
        a[kk] = s.v;
    }

    const int rbase = blockIdx.x * 64 + wid * 16 + quad * 4;
    const char* wtb = (const char*)WT + quad * 16;

    #pragma unroll
    for (int m = 0; m < 2; ++m) {
        unsigned short* out = m ? xwg : xwl;
        #pragma unroll
        for (int t = 0; t < 8; ++t) {            // t == output slice (cols t*16..t*16+15)
            const char* bp = wtb + m * 32768 + (t * 16 + cl) * 256;
            float4v acc = {0.f, 0.f, 0.f, 0.f};
            #pragma unroll
            for (int kk = 0; kk < 4; ++kk) {
                short8 b = *(const short8*)(bp + kk * 64);
                acc = __builtin_amdgcn_mfma_f32_16x16x32_bf16(a[kk], b, acc, 0, 0, 0);
            }
            #pragma unroll
            for (int r = 0; r < 4; ++r) {
                int ro = rbase + r;
                if (ro < n) out[((size_t)t * n + ro) * 16 + cl] = f2bf(acc[r]);
            }
        }
    }
}

// ---------- XCD-sharded gather: slice = blockIdx % 8; 8 edge-groups x 8 feat-lanes ----------
__global__ __launch_bounds__(256) void gather_kernel(
    const unsigned short* __restrict__ xwl, const unsigned short* __restrict__ xwg,
    const int* __restrict__ ptr, const int2* __restrict__ edata,
    const float* __restrict__ dinv,
    const float* __restrict__ A, const float* __restrict__ Lr,
    const float* __restrict__ bl, const float* __restrict__ bg,
    float* __restrict__ out, int n, int E)
{
    const int lane  = threadIdx.x & 63;
    const int slice = blockIdx.x & 7;
    const int node  = (blockIdx.x >> 3) * 4 + (threadIdx.x >> 6);
    if (node >= n) return;
    const int grp = lane >> 3;        // edge group 0..7
    const int fl  = lane & 7;         // feature pair 0..7 within slice

    float acc0 = 0.f, acc1 = 0.f;

    // ---- local graph ----
    {
        const int i0 = ptr[node], i1 = ptr[node + 1];
        const unsigned short* xs = xwl + (size_t)slice * n * 16 + 2 * fl;
        for (int chunk = i0; chunk < i1; chunk += 64) {
            int idx = chunk + lane;
            int2 ed = edata[idx < i1 ? idx : i1 - 1];
            float nmv = __int_as_float(ed.x);
            int   sv  = ed.y;
            int maxit = (i1 - chunk + 7) >> 3; if (maxit > 8) maxit = 8;
            for (int it = 0; it < maxit; ++it) {
                float nm = __shfl(nmv, grp + 8 * it);
                int   s  = __shfl(sv,  grp + 8 * it);
                if (chunk + grp + 8 * it < i1) {
                    unsigned int pk = *(const unsigned int*)&xs[(size_t)s * 16];
                    acc0 += nm * bf2f(pk & 0xffffu);
                    acc1 += nm * bf2f(pk >> 16);
                }
            }
        }
    }
    // ---- global graph ----
    {
        const int i0 = ptr[n + node];
        const int i1 = (node == n - 1) ? E : ptr[n + node + 1];
        const unsigned short* xs = xwg + (size_t)slice * n * 16 + 2 * fl;
        for (int chunk = i0; chunk < i1; chunk += 64) {
            int idx = chunk + lane;
            int2 ed = edata[idx < i1 ? idx : i1 - 1];
            float nmv = __int_as_float(ed.x);
            int   sv  = ed.y;
            int maxit = (i1 - chunk + 7) >> 3; if (maxit > 8) maxit = 8;
            for (int it = 0; it < maxit; ++it) {
                float nm = __shfl(nmv, grp + 8 * it);
                int   s  = __shfl(sv,  grp + 8 * it);
                if (chunk + grp + 8 * it < i1) {
                    unsigned int pk = *(const unsigned int*)&xs[(size_t)s * 16];
                    acc0 += nm * bf2f(pk & 0xffffu);
                    acc1 += nm * bf2f(pk >> 16);
                }
            }
        }
    }

    // cross-group reduction (groups differ in lane bits 3..5)
    acc0 += __shfl_xor(acc0, 8);  acc1 += __shfl_xor(acc1, 8);
    acc0 += __shfl_xor(acc0, 16); acc1 += __shfl_xor(acc1, 16);
    acc0 += __shfl_xor(acc0, 32); acc1 += __shfl_xor(acc1, 32);

    if (grp == 0) {
        float dl = dinv[node];     dl *= dl;
        float dg = dinv[n + node]; dg *= dg;
        unsigned int psl = *(const unsigned int*)&xwl[((size_t)slice * n + node) * 16 + 2 * fl];
        unsigned int psg = *(const unsigned int*)&xwg[((size_t)slice * n + node) * 16 + 2 * fl];
        acc0 += dl * bf2f(psl & 0xffffu) + dg * bf2f(psg & 0xffffu);
        acc1 += dl * bf2f(psl >> 16)     + dg * bf2f(psg >> 16);
        const int fo = slice * 16 + 2 * fl;
        const size_t base = (size_t)node * DFEAT + fo;
        float2 b1 = *(const float2*)&bl[fo];
        float2 b2 = *(const float2*)&bg[fo];
        float2 a2 = *(const float2*)&A[base];
        float2 l2 = *(const float2*)&Lr[base];
        float v0 = acc0 + b1.x + b2.x;
        float v1 = acc1 + b1.y + b2.y;
        float w0 = 1.0f / (1.0f + __expf(-v0));
        float w1 = 1.0f / (1.0f + __expf(-v1));
        float o0 = 2.0f * (a2.x * w0 + l2.x * (1.0f - w0));
        float o1 = 2.0f * (a2.y * w1 + l2.y * (1.0f - w1));
        *(float2*)&out[base] = make_float2(o0, o1);
    }
}

extern "C" void kernel_launch(void* const* d_in, const int* in_sizes, int n_in,
                              void* d_out, int out_size, void* d_ws, size_t ws_size,
                              hipStream_t stream)
{
    const float* activity = (const float*)d_in[0];
    const float* learning = (const float*)d_in[1];
    const int*   ei  = (const int*)d_in[2];
    const float* ew  = (const float*)d_in[3];
    const int*   gei = (const int*)d_in[4];
    const float* gew = (const float*)d_in[5];
    const float* Wl  = (const float*)d_in[6];
    const float* bl  = (const float*)d_in[7];
    const float* Wg  = (const float*)d_in[8];
    const float* bg  = (const float*)d_in[9];

    const int n  = in_sizes[0] / DFEAT;   // 50000
    const int El = in_sizes[3];           // 500000
    const int Eg = in_sizes[5];           // 600000
    const int n2 = 2 * n;
    const int E  = El + Eg;

    // ws layout (~38.3 MB):
    // [xwl bf16 sliced][xwg bf16 sliced][dc u64 2N][dinv f32 2N][ptr int 2N]
    // [bsum 2048B][WT bf16 64KB][edata int2 E][lp16 ushort E]
    char* ws = (char*)d_ws;
    const size_t xwBytes = (size_t)n * DFEAT * 2;
    unsigned short* xwl = (unsigned short*)ws;
    unsigned short* xwg = (unsigned short*)(ws + xwBytes);
    unsigned long long* dc = (unsigned long long*)(ws + 2 * xwBytes);
    float* dinv = (float*)(ws + 2 * xwBytes + (size_t)n2 * 8);
    int*   ptr  = (int*)(ws + 2 * xwBytes + (size_t)n2 * 12);
    int*   bsum = (int*)(ws + 2 * xwBytes + (size_t)n2 * 16);
    unsigned short* WT = (unsigned short*)(ws + 2 * xwBytes + (size_t)n2 * 16 + 2048);
    int2* edata = (int2*)(ws + 2 * xwBytes + (size_t)n2 * 16 + 2048 + 65536);
    unsigned short* lp16 = (unsigned short*)(ws + 2 * xwBytes + (size_t)n2 * 16 + 2048 + 65536
                                             + (size_t)E * 8);

    const int scanBlocks = (n2 + 255) / 256;       // 391

    hipMemsetAsync(dc, 0, (size_t)n2 * 8, stream);

    hist_kernel<<<dim3(128 + (E + 255) / 256), dim3(256), 0, stream>>>(
        ei + El, ew, gei + Eg, gew, Wl, Wg, WT, dc, lp16, El, Eg, n);

    scan1_kernel<<<dim3(scanBlocks), dim3(256), 0, stream>>>(dc, ptr, bsum, dinv, n2);
    scan2_kernel<<<dim3(1), dim3(512), 0, stream>>>(bsum, scanBlocks);
    scan3_kernel<<<dim3(scanBlocks), dim3(256), 0, stream>>>(ptr, bsum, n2);

    edata_write_kernel<<<dim3((E + 255) / 256), dim3(256), 0, stream>>>(
        ei, ei + El, ew, gei, gei + Eg, gew, dinv, ptr, lp16, edata, El, Eg, n);

    gemm_kernel<<<dim3((n + 63) / 64), dim3(256), 0, stream>>>(
        activity, learning, WT, xwl, xwg, n);

    gather_kernel<<<dim3(((n + 3) / 4) * 8), dim3(256), 0, stream>>>(
        xwl, xwg, ptr, edata, dinv, activity, learning, bl, bg, (float*)d_out, n, E);
}

// Round 9
// 282.942 us; speedup vs baseline: 1.4903x; 1.4903x over previous
//
#include <hip/hip_runtime.h>

#define DFEAT 128

typedef __attribute__((ext_vector_type(8))) short short8;
typedef __attribute__((ext_vector_type(4))) float float4v;

// ---------- bf16 helpers ----------
__device__ __forceinline__ float bf2f(unsigned int h) {
    union { unsigned int u; float f; } v; v.u = h << 16; return v.f;
}
__device__ __forceinline__ unsigned short f2bf(float f) {
    union { float f; unsigned int u; } v; v.f = f;
    unsigned int u = v.u;
    unsigned int lsb = (u >> 16) & 1u;
    u += 0x7fffu + lsb;               // RNE
    return (unsigned short)(u >> 16);
}

// ---------- kernel Z: blocks [0,128) transpose W -> WT bf16; rest zero dc ----------
__global__ __launch_bounds__(256) void zprep_kernel(
    const float* __restrict__ Wl, const float* __restrict__ Wg,
    unsigned short* __restrict__ WT,
    unsigned long long* __restrict__ dc, int n2)
{
    if (blockIdx.x < 128) {
        int idx = blockIdx.x * 256 + threadIdx.x;     // 0 .. 32767
        int m = idx >> 14, rem = idx & 16383;
        int k = rem >> 7, c = rem & 127;              // lanes -> c consecutive (coalesced read)
        const float* W = m ? Wg : Wl;
        WT[m * 16384 + c * 128 + k] = f2bf(W[k * 128 + c]);
        return;
    }
    int i = (blockIdx.x - 128) * 256 + threadIdx.x;
    if (i < n2) dc[i] = 0ULL;
}

// ---------- kernel A: fused MFMA dual-GEMM (blocks [0,GB)) + packed-u64 hist (rest) ----------
// hist: dc[t] += (1<<48)|(u64)(w*2^40); atomic RETURN -> edge's local position (lp16).
__global__ __launch_bounds__(256) void gemm_hist_kernel(
    const float* __restrict__ A, const float* __restrict__ L,
    const unsigned short* __restrict__ WT,   // [2][col 128][k 128] bf16
    unsigned short* __restrict__ xwl, unsigned short* __restrict__ xwg,
    const int* __restrict__ dstL, const float* __restrict__ wL,
    const int* __restrict__ dstG, const float* __restrict__ wG,
    unsigned long long* __restrict__ dc, unsigned short* __restrict__ lp16,
    int El, int Eg, int n, int GB)
{
    if (blockIdx.x >= GB) {
        // ---------------- histogram part ----------------
        int e = (blockIdx.x - GB) * 256 + threadIdx.x;
        if (e < El) {
            int t = dstL[e];
            unsigned long long add = (1ULL << 48) | (unsigned long long)(wL[e] * 0x1p40f);
            unsigned long long old = atomicAdd(&dc[t], add);
            lp16[e] = (unsigned short)(old >> 48);
        } else if (e < El + Eg) {
            int e2 = e - El;
            int t = dstG[e2];
            unsigned long long add = (1ULL << 48) | (unsigned long long)(wG[e2] * 0x1p40f);
            unsigned long long old = atomicAdd(&dc[n + t], add);
            lp16[e] = (unsigned short)(old >> 48);
        }
        return;
    }
    // ---------------- GEMM part ----------------
    const int tid  = threadIdx.x;
    const int wid  = tid >> 6;
    const int lane = tid & 63;
    const int quad = lane >> 4;
    const int cl   = lane & 15;

    int rowa = blockIdx.x * 64 + wid * 16 + cl;
    if (rowa > n - 1) rowa = n - 1;               // clamp (dup compute, stores predicated)

    const float* Ar = A + (size_t)rowa * DFEAT;
    const float* Lr = L + (size_t)rowa * DFEAT;

    short8 a[4];
    #pragma unroll
    for (int kk = 0; kk < 4; ++kk) {
        const int kb = kk * 32 + quad * 8;
        float4 a0 = *(const float4*)&Ar[kb];
        float4 a1 = *(const float4*)&Ar[kb + 4];
        float4 l0 = *(const float4*)&Lr[kb];
        float4 l1 = *(const float4*)&Lr[kb + 4];
        union { short8 v; unsigned short u[8]; } s;
        s.u[0] = f2bf(a0.x + l0.x); s.u[1] = f2bf(a0.y + l0.y);
        s.u[2] = f2bf(a0.z + l0.z); s.u[3] = f2bf(a0.w + l0.w);
        s.u[4] = f2bf(a1.x + l1.x); s.u[5] = f2bf(a1.y + l1.y);
        s.u[6] = f2bf(a1.z + l1.z); s.u[7] = f2bf(a1.w + l1.w);
        a[kk] = s.v;
    }

    const int rbase = blockIdx.x * 64 + wid * 16 + quad * 4;
    const char* wtb = (const char*)WT + quad * 16;

    #pragma unroll
    for (int m = 0; m < 2; ++m) {
        unsigned short* out = m ? xwg : xwl;
        #pragma unroll
        for (int t = 0; t < 8; ++t) {
            const int col = t * 16 + cl;
            const char* bp = wtb + m * 32768 + col * 256;
            float4v acc = {0.f, 0.f, 0.f, 0.f};
            #pragma unroll
            for (int kk = 0; kk < 4; ++kk) {
                short8 b = *(const short8*)(bp + kk * 64);
                acc = __builtin_amdgcn_mfma_f32_16x16x32_bf16(a[kk], b, acc, 0, 0, 0);
            }
            #pragma unroll
            for (int r = 0; r < 4; ++r) {
                int ro = rbase + r;
                if (ro < n) out[(size_t)ro * DFEAT + col] = f2bf(acc[r]);
            }
        }
    }
}

// ---------- scan stage 1: unpack dc -> (block-local excl scan into ptr, bsum, dinv) ----------
__global__ __launch_bounds__(256) void scan1_kernel(const unsigned long long* __restrict__ dc,
                                                    int* __restrict__ ptr,
                                                    int* __restrict__ bsum,
                                                    float* __restrict__ dinv, int n)
{
    __shared__ int tmp[256];
    int i = blockIdx.x * 256 + threadIdx.x;
    int v = 0;
    if (i < n) {
        unsigned long long d = dc[i];
        v = (int)(d >> 48);
        dinv[i] = rsqrtf((float)(d & ((1ULL << 48) - 1)) * 0x1p-40f + 1.0f);
    }
    tmp[threadIdx.x] = v;
    __syncthreads();
    for (int off = 1; off < 256; off <<= 1) {
        int t = (threadIdx.x >= off) ? tmp[threadIdx.x - off] : 0;
        __syncthreads();
        tmp[threadIdx.x] += t;
        __syncthreads();
    }
    if (i < n) ptr[i] = tmp[threadIdx.x] - v;       // exclusive within block
    if (threadIdx.x == 255) bsum[blockIdx.x] = tmp[255];
}

// ---------- scan stage 2: single block exclusive scan of bsum (nb <= 512) ----------
__global__ __launch_bounds__(512) void scan2_kernel(int* __restrict__ bsum, int nb)
{
    __shared__ int tmp[512];
    int i = threadIdx.x;
    int v = (i < nb) ? bsum[i] : 0;
    tmp[i] = v;
    __syncthreads();
    for (int off = 1; off < 512; off <<= 1) {
        int t = (i >= off) ? tmp[i - off] : 0;
        __syncthreads();
        tmp[i] += t;
        __syncthreads();
    }
    if (i < nb) bsum[i] = tmp[i] - v;
}

// ---------- edata placement: NO atomics; pos = ptr[t]+bsum[t>>8]+lp16[e] ----------
__global__ __launch_bounds__(256) void edata_write_kernel(
    const int* __restrict__ srcL, const int* __restrict__ dstL, const float* __restrict__ wL,
    const int* __restrict__ srcG, const int* __restrict__ dstG, const float* __restrict__ wG,
    const float* __restrict__ dinv, const int* __restrict__ ptr, const int* __restrict__ bsum,
    const unsigned short* __restrict__ lp16, int2* __restrict__ edata,
    int El, int Eg, int n)
{
    int e = blockIdx.x * 256 + threadIdx.x;
    if (e < El) {
        int s = srcL[e], t = dstL[e];
        float norm = dinv[s] * wL[e] * dinv[t];
        int pos = ptr[t] + bsum[t >> 8] + lp16[e];
        edata[pos] = make_int2(__float_as_int(norm), s);
    } else if (e < El + Eg) {
        int e2 = e - El;
        int s = srcG[e2], t = dstG[e2];
        float norm = dinv[n + s] * wG[e2] * dinv[n + t];
        int tt = n + t;
        int pos = ptr[tt] + bsum[tt >> 8] + lp16[e];
        edata[pos] = make_int2(__float_as_int(norm), s);
    }
}

// ---------- fused gather (r7 structure): shuffle-broadcast edge metadata ----------
__global__ __launch_bounds__(256) void gather_kernel(
    const unsigned short* __restrict__ xwl, const unsigned short* __restrict__ xwg,
    const int* __restrict__ ptr, const int* __restrict__ bsum, const int2* __restrict__ edata,
    const float* __restrict__ dinv,
    const float* __restrict__ A, const float* __restrict__ Lr,
    const float* __restrict__ bl, const float* __restrict__ bg,
    float* __restrict__ out, int n, int E)
{
    const int lane = threadIdx.x & 63;
    const int node = blockIdx.x * 4 + (threadIdx.x >> 6);
    if (node >= n) return;
    const int i0l = ptr[node] + bsum[node >> 8];
    const int i1l = ptr[node + 1] + bsum[(node + 1) >> 8];
    const int i0g = ptr[n + node] + bsum[(n + node) >> 8];
    const int i1g = (node == n - 1) ? E : ptr[n + node + 1] + bsum[(n + node + 1) >> 8];
    float dl = dinv[node];     dl *= dl;
    float dg = dinv[n + node]; dg *= dg;
    const int fo = 2 * lane;
    const size_t base = (size_t)node * DFEAT + fo;

    unsigned int psl = *(const unsigned int*)&xwl[base];
    unsigned int psg = *(const unsigned int*)&xwg[base];
    float acc0 = dl * bf2f(psl & 0xffffu) + dg * bf2f(psg & 0xffffu);
    float acc1 = dl * bf2f(psl >> 16)     + dg * bf2f(psg >> 16);

    // ---- local segment ----
    for (int b0 = i0l; b0 < i1l; b0 += 64) {
        int idx = b0 + lane;
        int2 ed = edata[idx < i1l ? idx : (i1l - 1)];
        float nmv = __int_as_float(ed.x);
        int   sv  = ed.y;
        int mcnt = i1l - b0; if (mcnt > 64) mcnt = 64;
        #pragma unroll 4
        for (int jj = 0; jj < mcnt; ++jj) {
            float nm = __shfl(nmv, jj);
            int   s  = __shfl(sv, jj);
            unsigned int pk = *(const unsigned int*)&xwl[(size_t)s * DFEAT + fo];
            acc0 += nm * bf2f(pk & 0xffffu);
            acc1 += nm * bf2f(pk >> 16);
        }
    }
    // ---- global segment ----
    for (int b0 = i0g; b0 < i1g; b0 += 64) {
        int idx = b0 + lane;
        int2 ed = edata[idx < i1g ? idx : (i1g - 1)];
        float nmv = __int_as_float(ed.x);
        int   sv  = ed.y;
        int mcnt = i1g - b0; if (mcnt > 64) mcnt = 64;
        #pragma unroll 4
        for (int jj = 0; jj < mcnt; ++jj) {
            float nm = __shfl(nmv, jj);
            int   s  = __shfl(sv, jj);
            unsigned int pk = *(const unsigned int*)&xwg[(size_t)s * DFEAT + fo];
            acc0 += nm * bf2f(pk & 0xffffu);
            acc1 += nm * bf2f(pk >> 16);
        }
    }

    float2 b1 = *(const float2*)&bl[fo];
    float2 b2 = *(const float2*)&bg[fo];
    float2 a2 = *(const float2*)&A[base];
    float2 l2 = *(const float2*)&Lr[base];
    float v0 = acc0 + b1.x + b2.x;
    float v1 = acc1 + b1.y + b2.y;
    float w0 = 1.0f / (1.0f + __expf(-v0));
    float w1 = 1.0f / (1.0f + __expf(-v1));
    float o0 = 2.0f * (a2.x * w0 + l2.x * (1.0f - w0));
    float o1 = 2.0f * (a2.y * w1 + l2.y * (1.0f - w1));
    *(float2*)&out[base] = make_float2(o0, o1);
}

extern "C" void kernel_launch(void* const* d_in, const int* in_sizes, int n_in,
                              void* d_out, int out_size, void* d_ws, size_t ws_size,
                              hipStream_t stream)
{
    const float* activity = (const float*)d_in[0];
    const float* learning = (const float*)d_in[1];
    const int*   ei  = (const int*)d_in[2];
    const float* ew  = (const float*)d_in[3];
    const int*   gei = (const int*)d_in[4];
    const float* gew = (const float*)d_in[5];
    const float* Wl  = (const float*)d_in[6];
    const float* bl  = (const float*)d_in[7];
    const float* Wg  = (const float*)d_in[8];
    const float* bg  = (const float*)d_in[9];

    const int n  = in_sizes[0] / DFEAT;   // 50000
    const int El = in_sizes[3];           // 500000
    const int Eg = in_sizes[5];           // 600000
    const int n2 = 2 * n;
    const int E  = El + Eg;

    // ws layout (~38.3 MB):
    // [xwl bf16][xwg bf16][dc u64 2N][dinv f32 2N][ptr int 2N][bsum 2048B][WT bf16 64KB]
    // [edata int2 E][lp16 ushort E]
    char* ws = (char*)d_ws;
    const size_t xwBytes = (size_t)n * DFEAT * 2;
    unsigned short* xwl = (unsigned short*)ws;
    unsigned short* xwg = (unsigned short*)(ws + xwBytes);
    unsigned long long* dc = (unsigned long long*)(ws + 2 * xwBytes);
    float* dinv = (float*)(ws + 2 * xwBytes + (size_t)n2 * 8);
    int*   ptr  = (int*)(ws + 2 * xwBytes + (size_t)n2 * 12);
    int*   bsum = (int*)(ws + 2 * xwBytes + (size_t)n2 * 16);
    unsigned short* WT = (unsigned short*)(ws + 2 * xwBytes + (size_t)n2 * 16 + 2048);
    int2* edata = (int2*)(ws + 2 * xwBytes + (size_t)n2 * 16 + 2048 + 65536);
    unsigned short* lp16 = (unsigned short*)(ws + 2 * xwBytes + (size_t)n2 * 16 + 2048 + 65536
                                             + (size_t)E * 8);

    const int scanBlocks = (n2 + 255) / 256;       // 391
    const int GB = (n + 63) / 64;                  // 782 gemm blocks
    const int HB = (E + 255) / 256;                // 4297 hist blocks

    zprep_kernel<<<dim3(128 + scanBlocks), dim3(256), 0, stream>>>(Wl, Wg, WT, dc, n2);

    gemm_hist_kernel<<<dim3(GB + HB), dim3(256), 0, stream>>>(
        activity, learning, WT, xwl, xwg,
        ei + El, ew, gei + Eg, gew, dc, lp16, El, Eg, n, GB);

    scan1_kernel<<<dim3(scanBlocks), dim3(256), 0, stream>>>(dc, ptr, bsum, dinv, n2);
    scan2_kernel<<<dim3(1), dim3(512), 0, stream>>>(bsum, scanBlocks);

    edata_write_kernel<<<dim3(HB), dim3(256), 0, stream>>>(
        ei, ei + El, ew, gei, gei + Eg, gew, dinv, ptr, bsum, lp16, edata, El, Eg, n);

    gather_kernel<<<dim3((n + 3) / 4), dim3(256), 0, stream>>>(
        xwl, xwg, ptr, bsum, edata, dinv, activity, learning, bl, bg, (float*)d_out, n, E);
}